// Round 6
// baseline (678.098 us; speedup 1.0000x reference)
//
#include <hip/hip_runtime.h>

#define NN 100000
#define EE 800000
#define HH 128
#define LL 4
#define GG 64
#define BN_EPS 1e-5f
#define LN_EPS 1e-5f
#define POOL_CHUNK 64
#define NBUK ((NN + 255) >> 8)   // 391 buckets of 256 rows
#define CAP 8192                 // fixed bucket capacity (max observed ~4.5k)
#define BCHUNK 8192
#define UPITCH 136               // u-tile row pitch in shorts (128 + 8 pad)
#define Q8SCALE 16.0f            // int8 shadow quantization scale (pow2: decode mul exact)
#define Q8INV   0.0625f

typedef __attribute__((ext_vector_type(8))) short short8;
typedef __attribute__((ext_vector_type(4))) float f32x4;

__device__ inline unsigned short bf16_rne(float f) {
    unsigned u = __float_as_uint(f);
    return (unsigned short)((u + 0x7FFF + ((u >> 16) & 1)) >> 16);
}
__device__ inline float bf16_to_f32(unsigned short h) {
    return __uint_as_float((unsigned)h << 16);
}

// ---------------- fused setup: zero scratch + init bcur + weight transpose/convert ----------------
// fragment order: element (n,k) of W^T at ((k>>3)*8 + (n>>4))*128 + (n&15)*8 + (k&7)

__global__ void setup_kernel(const float* __restrict__ W0, const float* __restrict__ W1,
                             const float* __restrict__ W2, short* __restrict__ wt_hi,
                             int* __restrict__ bcur, float* __restrict__ colsum,
                             float* __restrict__ psum, float* __restrict__ pcnt) {
    int i = blockIdx.x * 256 + threadIdx.x;
    if (i < NBUK) bcur[i] = i * CAP;
    if (i < LL * HH * 2) colsum[i] = 0.f;
    if (i < GG * HH) psum[i] = 0.f;
    if (i < GG) pcnt[i] = 0.f;
    if (i < 9 * HH * HH) {
        int mat = i >> 14, rem = i & 16383;
        int n = rem >> 7, k = rem & 127;
        const float* src = (mat == 0) ? W0 : ((mat <= 4) ? W1 + (size_t)(mat - 1) * HH * HH
                                                         : W2 + (size_t)(mat - 5) * HH * HH);
        float v = src[(size_t)k * HH + n];
        int off = (mat << 14) + (((k >> 3) * 8 + (n >> 4)) << 7) + ((n & 15) << 3) + (k & 7);
        wt_hi[off] = (short)bf16_rne(v);
    }
}

// ---------------- CSR build: fixed-capacity bucket sort (256 rows / bucket) ----------------

__global__ __launch_bounds__(256) void bucket_scatter(const int* __restrict__ ei, int* __restrict__ bcur,
                                                      int* __restrict__ pairs) {
    __shared__ int h[NBUK];
    __shared__ int curb[NBUK];
    int tid = threadIdx.x;
    for (int i = tid; i < NBUK; i += 256) h[i] = 0;
    __syncthreads();
    int base = blockIdx.x * BCHUNK;
#pragma unroll 4
    for (int k = 0; k < BCHUNK / 256; k++) {
        int e = base + k * 256 + tid;
        if (e < 2 * EE) {
            int r = ei[e];
            int c = (e < EE) ? ei[e + EE] : ei[e - EE];
            if (r != c) atomicAdd(&h[r >> 8], 1);
        }
    }
    __syncthreads();
    for (int i = tid; i < NBUK; i += 256) {
        int n = h[i];
        curb[i] = n ? atomicAdd(&bcur[i], n) : 0;
    }
    __syncthreads();
#pragma unroll 4
    for (int k = 0; k < BCHUNK / 256; k++) {
        int e = base + k * 256 + tid;
        if (e < 2 * EE) {
            int r = ei[e];
            int c = (e < EE) ? ei[e + EE] : ei[e - EE];
            if (r != c) {
                int p = atomicAdd(&curb[r >> 8], 1);
                pairs[p] = ((r & 255) << 17) | c;
            }
        }
    }
}

__global__ __launch_bounds__(256) void bucket_build(const int* __restrict__ pairs, const int* __restrict__ bcur,
                                                    int* __restrict__ rp, int* __restrict__ re,
                                                    int* __restrict__ colidx) {
    __shared__ int hist[256], off[256], lcol[CAP];
    int b = blockIdx.x, tid = threadIdx.x;
    int s = b * CAP;
    int size = bcur[b] - s;
    hist[tid] = 0;
    __syncthreads();
    for (int i = tid; i < size; i += 256) atomicAdd(&hist[pairs[s + i] >> 17], 1);
    __syncthreads();
    off[tid] = hist[tid];
    __syncthreads();
    for (int o = 1; o < 256; o <<= 1) {
        int x = (tid >= o) ? off[tid - o] : 0;
        __syncthreads();
        off[tid] += x;
        __syncthreads();
    }
    int excl = (tid > 0) ? off[tid - 1] : 0;
    int r = (b << 8) + tid;
    if (r < NN) { rp[r] = s + excl; re[r] = s + off[tid]; }
    hist[tid] = excl;
    __syncthreads();
    for (int i = tid; i < size; i += 256) {
        int u = pairs[s + i];
        int p = atomicAdd(&hist[u >> 17], 1);
        lcol[p] = u & 0x1FFFF;
    }
    __syncthreads();
    for (int i = tid; i < size; i += 256) colidx[s + i] = lcol[i];
}

// ---------------- fused agg + GEMM1 v5 (r4 proven, byte-identical): int8 gather ----------------
// Phase A: half-wave (32 lanes x 4B = one 128B int8 row) gathers 8 rows serially, 8-deep
//          pipelined, register accumulation; self row exact bf16.
// Phase B: u-tile -> bf16 A-frags; W from global (L1-resident, fragment order); MFMA;
//          z1 staged through same LDS; column stats.
// Evidence: (a) 16B/lane gather spills (r1/r2: 280/102 MB scratch WRITE). Keep 4B/lane.
//           (b) 32-row blocks: occupancy 47->64% but SLOWER (r3). Keep 64 rows.
//           (c) int8 shadow halved FETCH 190->94 MB, -19us, absmax unchanged (r4).
//           (d) sentinel-pad + LDS-colidx + packed-add REGRESSED 87->96 (r5). Do not touch.

__global__ __launch_bounds__(256, 6) void fused_g1(
    const uint2* __restrict__ hbf2,
    const unsigned int* __restrict__ h8,
    const int* __restrict__ rp, const int* __restrict__ re,
    const int* __restrict__ colidx,
    const float* __restrict__ eps_l, int layer,
    const short* __restrict__ wt,
    const float* __restrict__ bias,
    unsigned short* __restrict__ z1_out,
    float* __restrict__ colsum, float* __restrict__ colsq)
{
    __shared__ __align__(16) unsigned short uls[64 * UPITCH];   // 17.4 KB bf16 u-tile / z1 stage
    __shared__ float stats[2 * HH];
    int tid = threadIdx.x;
    int wave = tid >> 6, lane = tid & 63;
    int half = lane >> 5, sub = lane & 31;
    int lrow = lane & 15, kgrp = lane >> 4;
    int r0 = blockIdx.x * 64;
    stats[tid] = 0.f;
    float eps1 = 1.0f + eps_l[layer];

    // ---- phase A: gather 8 rows per half-wave; lane covers feats 4*sub..4*sub+3 ----
    int hw = wave * 2 + half;   // 0..7
    for (int rl = 0; rl < 8; rl++) {
        int row = hw * 8 + rl;
        int r = r0 + row;
        float a0 = 0.f, a1 = 0.f, a2 = 0.f, a3 = 0.f;
        uint2 sv = make_uint2(0u, 0u);
        if (r < NN) {
            sv = hbf2[(size_t)r * 32 + sub];   // exact bf16 self row (latency hidden by loop)
            int base = rp[r];
            int n = re[r] - base;
            for (int i = 0; i < n; i += 8) {
                unsigned v[8];
                int c[8];
#pragma unroll
                for (int j = 0; j < 8; j++) c[j] = (i + j < n) ? colidx[base + i + j] : -1;
#pragma unroll
                for (int j = 0; j < 8; j++)
                    v[j] = (c[j] >= 0) ? h8[(size_t)c[j] * 32 + sub] : 0u;
#pragma unroll
                for (int j = 0; j < 8; j++) {
                    a0 += (float)((int)(v[j] << 24) >> 24);
                    a1 += (float)((int)(v[j] << 16) >> 24);
                    a2 += (float)((int)(v[j] <<  8) >> 24);
                    a3 += (float)((int)v[j] >> 24);
                }
            }
        }
        // scale int8 sum once; add exact (1+eps)*self
        a0 = fmaf(bf16_to_f32((unsigned short)(sv.x & 0xFFFF)), eps1, a0 * Q8INV);
        a1 = fmaf(bf16_to_f32((unsigned short)(sv.x >> 16)),    eps1, a1 * Q8INV);
        a2 = fmaf(bf16_to_f32((unsigned short)(sv.y & 0xFFFF)), eps1, a2 * Q8INV);
        a3 = fmaf(bf16_to_f32((unsigned short)(sv.y >> 16)),    eps1, a3 * Q8INV);
        uint2 o;
        o.x = (unsigned)bf16_rne(a0) | ((unsigned)bf16_rne(a1) << 16);
        o.y = (unsigned)bf16_rne(a2) | ((unsigned)bf16_rne(a3) << 16);
        *(uint2*)&uls[row * UPITCH + sub * 4] = o;
    }
    __syncthreads();

    // ---- A-frags from bf16 u-tile ----
    short8 az[4];
#pragma unroll
    for (int ks = 0; ks < 4; ks++)
        az[ks] = *(const short8*)&uls[(wave * 16 + lrow) * UPITCH + ks * 32 + kgrp * 8];
    __syncthreads();   // frag reads done; uls reusable for z1 staging

    // ---- MFMA: W from global (32 KB, L1-resident, fragment order) ----
    f32x4 acc[8];
#pragma unroll
    for (int c = 0; c < 8; c++) acc[c] = (f32x4){0.f, 0.f, 0.f, 0.f};
#pragma unroll
    for (int ks = 0; ks < 4; ks++) {
        int fb = (ks * 4 + kgrp) * 8;
#pragma unroll
        for (int c = 0; c < 8; c++) {
            short8 whi = *(const short8*)(wt + (size_t)((fb + c) << 7) + (lrow << 3));
            acc[c] = __builtin_amdgcn_mfma_f32_16x16x32_bf16(az[ks], whi, acc[c], 0, 0, 0);
        }
    }

    // ---- epilogue: z1 bf16 out (staged through uls) + column stats ----
    float bv[8];
#pragma unroll
    for (int c = 0; c < 8; c++) bv[c] = bias[c * 16 + lrow];
    int lrb = wave * 16 + kgrp * 4;
    float ps[8], pq[8];
#pragma unroll
    for (int c = 0; c < 8; c++) { ps[c] = 0.f; pq[c] = 0.f; }
#pragma unroll
    for (int c = 0; c < 8; c++)
#pragma unroll
        for (int reg = 0; reg < 4; reg++) {
            float z = acc[c][reg] + bv[c];
            uls[(lrb + reg) * UPITCH + c * 16 + lrow] = bf16_rne(z);
            if (r0 + lrb + reg < NN) { ps[c] += z; pq[c] += z * z; }
        }
#pragma unroll
    for (int c = 0; c < 8; c++) {
        ps[c] += __shfl_xor(ps[c], 16); pq[c] += __shfl_xor(pq[c], 16);
        ps[c] += __shfl_xor(ps[c], 32); pq[c] += __shfl_xor(pq[c], 32);
    }
    if (kgrp == 0) {
#pragma unroll
        for (int c = 0; c < 8; c++) {
            atomicAdd(&stats[c * 16 + lrow], ps[c]);
            atomicAdd(&stats[HH + c * 16 + lrow], pq[c]);
        }
    }
    __syncthreads();
#pragma unroll
    for (int i = 0; i < 4; i++) {
        int idx = tid + i * 256;
        int row = idx >> 4;
        int r = r0 + row;
        if (r < NN)
            *(uint4*)(z1_out + (size_t)r * HH + (idx & 15) * 8) =
                *(const uint4*)&uls[row * UPITCH + (idx & 15) * 8];
    }
    if (tid < HH) {
        atomicAdd(&colsum[tid], stats[tid]);
        atomicAdd(&colsq[tid], stats[HH + tid]);
    }
}

// ---------------- GEMM v10 (modes 0 and 2): W from GLOBAL, small LDS, higher occupancy -------
// MODE 0: hbf = bf16(x @ W0 + bias)                       [A fp32, split-bf16]
// MODE 2: A' = relu(BN(z1)); hbf = bf16(LN(h_old + relu(A'@W2 + bias)))   [A = z1 bf16]
// Both emit the int8 shadow h8 (scale Q8SCALE) if h8out != 0.
// v10 change (r6): dropped the 32 KB W LDS stage + barrier — K-loop reads wt directly from
// global in fragment order (L1/L2-resident; the pattern fused_g1 phase B already proves).
// LDS 33.8 -> 17.5 KB; mode-2 occupancy 4 -> 6 blocks/CU. Mode-2 old-h residual tile is
// pre-staged into LDS before the K-loop (TLP hides its latency).

template<int MODE>
__global__ __launch_bounds__(256, (MODE == 2) ? 6 : 4) void gemm_v9(
    const void* __restrict__ Ain,
    const short* __restrict__ wt,
    const float* __restrict__ bias,
    const float* __restrict__ colsum, const float* __restrict__ colsq,
    const float* __restrict__ bng, const float* __restrict__ bnb,
    const float* __restrict__ lng, const float* __restrict__ lnb,
    unsigned short* __restrict__ hbf,
    unsigned int* __restrict__ h8out)
{
    __shared__ __align__(16) unsigned short hst[64 * HH];   // 16 KB bf16 row-tile stage
    __shared__ float stats[2 * HH];                          // mode2: bsc|bsh
    int tid = threadIdx.x;
    int wave = tid >> 6, lane = tid & 63;
    int lrow = lane & 15, kgrp = lane >> 4;
    int r0 = blockIdx.x * 64;
    int arow = r0 + wave * 16 + lrow;

    if (MODE == 2 && tid < HH) {
        float m = colsum[tid] * (1.f / NN);
        float v = colsq[tid] * (1.f / NN) - m * m;
        float a = bng[tid] * rsqrtf(v + BN_EPS);
        stats[tid] = a;
        stats[HH + tid] = bnb[tid] - m * a;
    }

    float4 a0[4], a1[4];
    short8 az[4];
    if (MODE == 2) {
        const unsigned short* Az = (const unsigned short*)Ain;
        if (arow < NN) {
#pragma unroll
            for (int ks = 0; ks < 4; ks++)
                az[ks] = *(const short8*)(Az + (size_t)arow * HH + ks * 32 + kgrp * 8);
        } else {
#pragma unroll
            for (int ks = 0; ks < 4; ks++) az[ks] = (short8){0,0,0,0,0,0,0,0};
        }
        // pre-stage old-h residual tile (coalesced); consumed in the epilogue
#pragma unroll
        for (int i = 0; i < 4; i++) {
            int idx = tid + i * 256;
            int r = r0 + (idx >> 4);
            uint4 v = make_uint4(0, 0, 0, 0);
            if (r < NN) v = *(const uint4*)(hbf + (size_t)r * HH + (idx & 15) * 8);
            ((uint4*)hst)[idx] = v;
        }
    } else {
        const float* Af = (const float*)Ain;
        if (arow < NN) {
#pragma unroll
            for (int ks = 0; ks < 4; ks++) {
                int kb = ks * 32 + kgrp * 8;
                a0[ks] = *(const float4*)(Af + (size_t)arow * HH + kb);
                a1[ks] = *(const float4*)(Af + (size_t)arow * HH + kb + 4);
            }
        } else {
#pragma unroll
            for (int ks = 0; ks < 4; ks++) {
                a0[ks] = make_float4(0.f, 0.f, 0.f, 0.f);
                a1[ks] = a0[ks];
            }
        }
    }
    __syncthreads();   // stats + old-h stage visible

    f32x4 acc[8];
#pragma unroll
    for (int c = 0; c < 8; c++) acc[c] = (f32x4){0.f, 0.f, 0.f, 0.f};

#pragma unroll
    for (int ks = 0; ks < 4; ks++) {
        int fb = (ks * 4 + kgrp) * 8;
        int kb = ks * 32 + kgrp * 8;
        float av[8];
        if (MODE == 2) {
#pragma unroll
            for (int j = 0; j < 8; j++) {
                float zb = bf16_to_f32((unsigned short)az[ks][j]);
                av[j] = fmaxf(fmaf(zb, stats[kb + j], stats[HH + kb + j]), 0.f);
            }
        } else {
            av[0] = a0[ks].x; av[1] = a0[ks].y; av[2] = a0[ks].z; av[3] = a0[ks].w;
            av[4] = a1[ks].x; av[5] = a1[ks].y; av[6] = a1[ks].z; av[7] = a1[ks].w;
        }
        short8 ahi, alo;
#pragma unroll
        for (int j = 0; j < 8; j++) {
            unsigned short hb = bf16_rne(av[j]);
            ahi[j] = (short)hb;
            alo[j] = (short)bf16_rne(av[j] - bf16_to_f32(hb));
        }
#pragma unroll
        for (int c = 0; c < 8; c++) {
            short8 whi = *(const short8*)(wt + (size_t)((fb + c) << 7) + (lrow << 3));
            acc[c] = __builtin_amdgcn_mfma_f32_16x16x32_bf16(ahi, whi, acc[c], 0, 0, 0);
            acc[c] = __builtin_amdgcn_mfma_f32_16x16x32_bf16(alo, whi, acc[c], 0, 0, 0);
        }
    }

    float bv[8];
#pragma unroll
    for (int c = 0; c < 8; c++) bv[c] = bias[c * 16 + lrow];
    int lrb = wave * 16 + kgrp * 4;

    if (MODE == 0) {
#pragma unroll
        for (int c = 0; c < 8; c++)
#pragma unroll
            for (int reg = 0; reg < 4; reg++)
                hst[(lrb + reg) * HH + c * 16 + lrow] = bf16_rne(acc[c][reg] + bv[c]);
        __syncthreads();
#pragma unroll
        for (int i = 0; i < 4; i++) {
            int idx = tid + i * 256;
            int r = r0 + (idx >> 4);
            if (r < NN)
                *(uint4*)(hbf + (size_t)r * HH + (idx & 15) * 8) = ((const uint4*)hst)[idx];
        }
    } else {
        float lg[8], lb[8];
#pragma unroll
        for (int c = 0; c < 8; c++) {
            lg[c] = lng[c * 16 + lrow];
            lb[c] = lnb[c * 16 + lrow];
        }
        // per-reg: residual + relu + LN on this wave's own 16 rows (staged pre-K-loop)
#pragma unroll
        for (int reg = 0; reg < 4; reg++) {
            int r = r0 + lrb + reg;
            if (r < NN) {   // uniform within each 16-lane shfl group
                float tv[8];
                float s = 0.f, q = 0.f;
#pragma unroll
                for (int c = 0; c < 8; c++) {
                    float hold = bf16_to_f32(hst[(lrb + reg) * HH + c * 16 + lrow]);
                    tv[c] = hold + fmaxf(acc[c][reg] + bv[c], 0.f);
                    s += tv[c]; q += tv[c] * tv[c];
                }
#pragma unroll
                for (int m = 1; m < 16; m <<= 1) {
                    s += __shfl_xor(s, m);
                    q += __shfl_xor(q, m);
                }
                float mu = s * (1.f / 128.f);
                float var = q * (1.f / 128.f) - mu * mu;
                float rs = rsqrtf(var + LN_EPS);
#pragma unroll
                for (int c = 0; c < 8; c++)
                    hst[(lrb + reg) * HH + c * 16 + lrow] =
                        bf16_rne((tv[c] - mu) * rs * lg[c] + lb[c]);
            }
        }
        __syncthreads();
#pragma unroll
        for (int i = 0; i < 4; i++) {
            int idx = tid + i * 256;
            int r = r0 + (idx >> 4);
            if (r < NN)
                *(uint4*)(hbf + (size_t)r * HH + (idx & 15) * 8) = ((const uint4*)hst)[idx];
        }
    }

    // ---- int8 shadow of h for the gather path (hst holds final bf16 tile) ----
    if (h8out) {
#pragma unroll
        for (int i = 0; i < 2; i++) {
            int idx = tid + i * 256;          // 512 slots: 64 rows x 8 groups of 16 feats
            int row = idx >> 3, q = idx & 7;
            int r = r0 + row;
            if (r < NN) {
                unsigned w[4];
#pragma unroll
                for (int k = 0; k < 4; k++) {
                    uint2 d = *(const uint2*)&hst[row * HH + q * 16 + k * 4];
                    float f0 = bf16_to_f32((unsigned short)(d.x & 0xFFFF));
                    float f1 = bf16_to_f32((unsigned short)(d.x >> 16));
                    float f2 = bf16_to_f32((unsigned short)(d.y & 0xFFFF));
                    float f3 = bf16_to_f32((unsigned short)(d.y >> 16));
                    int q0 = (int)rintf(fminf(fmaxf(f0 * Q8SCALE, -127.f), 127.f));
                    int q1 = (int)rintf(fminf(fmaxf(f1 * Q8SCALE, -127.f), 127.f));
                    int q2 = (int)rintf(fminf(fmaxf(f2 * Q8SCALE, -127.f), 127.f));
                    int q3 = (int)rintf(fminf(fmaxf(f3 * Q8SCALE, -127.f), 127.f));
                    w[k] = (unsigned)(q0 & 255) | ((unsigned)(q1 & 255) << 8) |
                           ((unsigned)(q2 & 255) << 16) | ((unsigned)(q3 & 255) << 24);
                }
                *(uint4*)(h8out + (size_t)r * 32 + q * 4) = make_uint4(w[0], w[1], w[2], w[3]);
            }
        }
    }
}

// ---------------- pooling (reads bf16 h) ----------------

__global__ void pool_kernel(const unsigned short* __restrict__ h, const int* __restrict__ batch,
                            float* __restrict__ psum, float* __restrict__ pcnt)
{
    int t = threadIdx.x;  // 128
    int n0 = blockIdx.x * POOL_CHUNK;
    int n1 = n0 + POOL_CHUNK; if (n1 > NN) n1 = NN;
    if (n0 >= NN) return;
    float acc = 0.f;
    int cur = batch[n0];
    int cnt = 0;
    for (int n = n0; n < n1; n++) {
        int g = batch[n];
        if (g != cur) {
            atomicAdd(&psum[cur * HH + t], acc);
            if (t == 0) atomicAdd(&pcnt[cur], (float)cnt);
            acc = 0.f; cnt = 0; cur = g;
        }
        acc += bf16_to_f32(h[(size_t)n * HH + t]);
        cnt++;
    }
    atomicAdd(&psum[cur * HH + t], acc);
    if (t == 0) atomicAdd(&pcnt[cur], (float)cnt);
}

__global__ void pool_final(const float* __restrict__ psum, const float* __restrict__ pcnt,
                           float* __restrict__ out)
{
    int i = blockIdx.x * blockDim.x + threadIdx.x;
    if (i < GG * HH) {
        float c = pcnt[i >> 7];
        out[i] = psum[i] / fmaxf(c, 1.f);
    }
}

// ---------------- launch ----------------

extern "C" void kernel_launch(void* const* d_in, const int* in_sizes, int n_in,
                              void* d_out, int out_size, void* d_ws, size_t ws_size,
                              hipStream_t stream)
{
    const float* x     = (const float*)d_in[0];
    const float* W0    = (const float*)d_in[1];
    const float* b0    = (const float*)d_in[2];
    const float* eps_l = (const float*)d_in[3];
    const float* W1    = (const float*)d_in[4];
    const float* b1    = (const float*)d_in[5];
    const float* bng   = (const float*)d_in[6];
    const float* bnb   = (const float*)d_in[7];
    const float* W2    = (const float*)d_in[8];
    const float* b2    = (const float*)d_in[9];
    const float* lng   = (const float*)d_in[10];
    const float* lnb   = (const float*)d_in[11];
    const int*   ei    = (const int*)d_in[12];
    const int*   batch = (const int*)d_in[13];
    float* out = (float*)d_out;

    char* ws = (char*)d_ws;
    size_t off = 0;
    auto alloc = [&](size_t bytes) -> void* {
        void* p = ws + off;
        off += (bytes + 255) & ~(size_t)255;
        return p;
    };
    unsigned short* hbf = (unsigned short*)alloc((size_t)NN * HH * 2);  // h (bf16)
    unsigned short* z1  = (unsigned short*)alloc((size_t)NN * HH * 2);  // z1 (bf16)
    unsigned int*   h8  = (unsigned int*)alloc((size_t)NN * HH);        // h (int8 shadow, 12.8 MB)
    int*   colidx = (int*)alloc((size_t)NBUK * CAP * 4 + 1024);         // +pad for 8-deep read
    int*   pairs  = (int*)alloc((size_t)NBUK * CAP * 4);
    int*   rp     = (int*)alloc((size_t)NN * 4);
    int*   re     = (int*)alloc((size_t)NN * 4);
    int*   bcur   = (int*)alloc((NBUK + 1) * 4);
    float* colsum = (float*)alloc((size_t)LL * HH * 2 * 4);  // [l][sum|sq][HH]
    float* psum   = (float*)alloc((size_t)GG * HH * 4);
    float* pcnt   = (float*)alloc(GG * 4);
    short* wt_hi  = (short*)alloc((size_t)9 * HH * HH * 2);

    // fused: zero colsum/psum/pcnt + bcur init + weight convert
    setup_kernel<<<(9 * HH * HH + 255) / 256, 256, 0, stream>>>(W0, W1, W2, wt_hi, bcur,
                                                                colsum, psum, pcnt);

    bucket_scatter<<<(2 * EE + BCHUNK - 1) / BCHUNK, 256, 0, stream>>>(ei, bcur, pairs);
    bucket_build<<<NBUK, 256, 0, stream>>>(pairs, bcur, rp, re, colidx);

    int gb = (NN + 63) / 64;
    // encode: h = bf16(x @ W0 + b0), + int8 shadow
    gemm_v9<0><<<gb, 256, 0, stream>>>(x, wt_hi, b0,
                                       nullptr, nullptr, nullptr, nullptr, nullptr, nullptr,
                                       hbf, h8);

    for (int l = 0; l < LL; l++) {
        float* cs = colsum + (size_t)l * HH * 2;
        float* cq = cs + HH;
        // z1 = bf16(((1+eps)h + sum_nb h) @ W1 + b1) + col stats  (agg from int8 shadow)
        fused_g1<<<gb, 256, 0, stream>>>((const uint2*)hbf, h8, rp, re, colidx, eps_l, l,
                                         wt_hi + (size_t)(1 + l) * HH * HH, b1 + l * HH, z1,
                                         cs, cq);
        // h = bf16(LN(h + relu(relu(BN(z1)) @ W2 + b2))), + int8 shadow (skip last layer)
        gemm_v9<2><<<gb, 256, 0, stream>>>(z1, wt_hi + (size_t)(5 + l) * HH * HH,
                                           b2 + l * HH,
                                           cs, cq, bng + l * HH, bnb + l * HH,
                                           lng + l * HH, lnb + l * HH, hbf,
                                           (l < LL - 1) ? h8 : nullptr);
    }

    pool_kernel<<<(NN + POOL_CHUNK - 1) / POOL_CHUNK, 128, 0, stream>>>(hbf, batch, psum, pcnt);
    pool_final<<<(GG * HH + 255) / 256, 256, 0, stream>>>(psum, pcnt, out);
}

// Round 7
// 601.948 us; speedup vs baseline: 1.1265x; 1.1265x over previous
//
#include <hip/hip_runtime.h>

#define NN 100000
#define EE 800000
#define HH 128
#define LL 4
#define GG 64
#define BN_EPS 1e-5f
#define LN_EPS 1e-5f
#define NBUK ((NN + 255) >> 8)   // 391 buckets of 256 rows
#define CAP 8192                 // fixed bucket capacity (max observed ~4.5k)
#define BCHUNK 8192
#define UPITCH 136               // u-tile row pitch in shorts (128 + 8 pad)
#define Q8SCALE 16.0f            // int8 shadow quantization scale (pow2: decode mul exact)
#define Q8INV   0.0625f

typedef __attribute__((ext_vector_type(8))) short short8;
typedef __attribute__((ext_vector_type(4))) float f32x4;

__device__ inline unsigned short bf16_rne(float f) {
    unsigned u = __float_as_uint(f);
    return (unsigned short)((u + 0x7FFF + ((u >> 16) & 1)) >> 16);
}
__device__ inline float bf16_to_f32(unsigned short h) {
    return __uint_as_float((unsigned)h << 16);
}

// ---------------- fused setup: zero scratch + init bcur + weight transpose/convert ----------------
// fragment order: element (n,k) of W^T at ((k>>3)*8 + (n>>4))*128 + (n&15)*8 + (k&7)

__global__ void setup_kernel(const float* __restrict__ W0, const float* __restrict__ W1,
                             const float* __restrict__ W2, short* __restrict__ wt_hi,
                             int* __restrict__ bcur, float* __restrict__ colsum,
                             float* __restrict__ psum, float* __restrict__ pcnt) {
    int i = blockIdx.x * 256 + threadIdx.x;
    if (i < NBUK) bcur[i] = i * CAP;
    if (i < LL * HH * 2) colsum[i] = 0.f;
    if (i < GG * HH) psum[i] = 0.f;
    if (i < GG) pcnt[i] = 0.f;
    if (i < 9 * HH * HH) {
        int mat = i >> 14, rem = i & 16383;
        int n = rem >> 7, k = rem & 127;
        const float* src = (mat == 0) ? W0 : ((mat <= 4) ? W1 + (size_t)(mat - 1) * HH * HH
                                                         : W2 + (size_t)(mat - 5) * HH * HH);
        float v = src[(size_t)k * HH + n];
        int off = (mat << 14) + (((k >> 3) * 8 + (n >> 4)) << 7) + ((n & 15) << 3) + (k & 7);
        wt_hi[off] = (short)bf16_rne(v);
    }
}

// ---------------- CSR build: fixed-capacity bucket sort (256 rows / bucket) ----------------

__global__ __launch_bounds__(256) void bucket_scatter(const int* __restrict__ ei, int* __restrict__ bcur,
                                                      int* __restrict__ pairs) {
    __shared__ int h[NBUK];
    __shared__ int curb[NBUK];
    int tid = threadIdx.x;
    for (int i = tid; i < NBUK; i += 256) h[i] = 0;
    __syncthreads();
    int base = blockIdx.x * BCHUNK;
#pragma unroll 4
    for (int k = 0; k < BCHUNK / 256; k++) {
        int e = base + k * 256 + tid;
        if (e < 2 * EE) {
            int r = ei[e];
            int c = (e < EE) ? ei[e + EE] : ei[e - EE];
            if (r != c) atomicAdd(&h[r >> 8], 1);
        }
    }
    __syncthreads();
    for (int i = tid; i < NBUK; i += 256) {
        int n = h[i];
        curb[i] = n ? atomicAdd(&bcur[i], n) : 0;
    }
    __syncthreads();
#pragma unroll 4
    for (int k = 0; k < BCHUNK / 256; k++) {
        int e = base + k * 256 + tid;
        if (e < 2 * EE) {
            int r = ei[e];
            int c = (e < EE) ? ei[e + EE] : ei[e - EE];
            if (r != c) {
                int p = atomicAdd(&curb[r >> 8], 1);
                pairs[p] = ((r & 255) << 17) | c;
            }
        }
    }
}

__global__ __launch_bounds__(256) void bucket_build(const int* __restrict__ pairs, const int* __restrict__ bcur,
                                                    int* __restrict__ rp, int* __restrict__ re,
                                                    int* __restrict__ colidx) {
    __shared__ int hist[256], off[256], lcol[CAP];
    int b = blockIdx.x, tid = threadIdx.x;
    int s = b * CAP;
    int size = bcur[b] - s;
    hist[tid] = 0;
    __syncthreads();
    for (int i = tid; i < size; i += 256) atomicAdd(&hist[pairs[s + i] >> 17], 1);
    __syncthreads();
    off[tid] = hist[tid];
    __syncthreads();
    for (int o = 1; o < 256; o <<= 1) {
        int x = (tid >= o) ? off[tid - o] : 0;
        __syncthreads();
        off[tid] += x;
        __syncthreads();
    }
    int excl = (tid > 0) ? off[tid - 1] : 0;
    int r = (b << 8) + tid;
    if (r < NN) { rp[r] = s + excl; re[r] = s + off[tid]; }
    hist[tid] = excl;
    __syncthreads();
    for (int i = tid; i < size; i += 256) {
        int u = pairs[s + i];
        int p = atomicAdd(&hist[u >> 17], 1);
        lcol[p] = u & 0x1FFFF;
    }
    __syncthreads();
    for (int i = tid; i < size; i += 256) colidx[s + i] = lcol[i];
}

// ---------------- fused agg + GEMM1 v5 (r4 proven, byte-identical): int8 gather ----------------
// Phase A: half-wave (32 lanes x 4B = one 128B int8 row) gathers 8 rows serially, 8-deep
//          pipelined, register accumulation; self row exact bf16.
// Phase B: u-tile -> bf16 A-frags; W from global (L1-resident, fragment order); MFMA;
//          z1 staged through same LDS; column stats.
// Evidence: (a) 16B/lane gather spills (r1/r2: 280/102 MB scratch WRITE). Keep 4B/lane.
//           (b) 32-row blocks: occupancy 47->64% but SLOWER (r3). Keep 64 rows.
//           (c) int8 shadow halved FETCH 190->94 MB, -19us, absmax unchanged (r4).
//           (d) sentinel-pad + LDS-colidx + packed-add REGRESSED 87->96 (r5). Do not touch.

__global__ __launch_bounds__(256, 6) void fused_g1(
    const uint2* __restrict__ hbf2,
    const unsigned int* __restrict__ h8,
    const int* __restrict__ rp, const int* __restrict__ re,
    const int* __restrict__ colidx,
    const float* __restrict__ eps_l, int layer,
    const short* __restrict__ wt,
    const float* __restrict__ bias,
    unsigned short* __restrict__ z1_out,
    float* __restrict__ colsum, float* __restrict__ colsq)
{
    __shared__ __align__(16) unsigned short uls[64 * UPITCH];   // 17.4 KB bf16 u-tile / z1 stage
    __shared__ float stats[2 * HH];
    int tid = threadIdx.x;
    int wave = tid >> 6, lane = tid & 63;
    int half = lane >> 5, sub = lane & 31;
    int lrow = lane & 15, kgrp = lane >> 4;
    int r0 = blockIdx.x * 64;
    stats[tid] = 0.f;
    float eps1 = 1.0f + eps_l[layer];

    // ---- phase A: gather 8 rows per half-wave; lane covers feats 4*sub..4*sub+3 ----
    int hw = wave * 2 + half;   // 0..7
    for (int rl = 0; rl < 8; rl++) {
        int row = hw * 8 + rl;
        int r = r0 + row;
        float a0 = 0.f, a1 = 0.f, a2 = 0.f, a3 = 0.f;
        uint2 sv = make_uint2(0u, 0u);
        if (r < NN) {
            sv = hbf2[(size_t)r * 32 + sub];   // exact bf16 self row (latency hidden by loop)
            int base = rp[r];
            int n = re[r] - base;
            for (int i = 0; i < n; i += 8) {
                unsigned v[8];
                int c[8];
#pragma unroll
                for (int j = 0; j < 8; j++) c[j] = (i + j < n) ? colidx[base + i + j] : -1;
#pragma unroll
                for (int j = 0; j < 8; j++)
                    v[j] = (c[j] >= 0) ? h8[(size_t)c[j] * 32 + sub] : 0u;
#pragma unroll
                for (int j = 0; j < 8; j++) {
                    a0 += (float)((int)(v[j] << 24) >> 24);
                    a1 += (float)((int)(v[j] << 16) >> 24);
                    a2 += (float)((int)(v[j] <<  8) >> 24);
                    a3 += (float)((int)v[j] >> 24);
                }
            }
        }
        // scale int8 sum once; add exact (1+eps)*self
        a0 = fmaf(bf16_to_f32((unsigned short)(sv.x & 0xFFFF)), eps1, a0 * Q8INV);
        a1 = fmaf(bf16_to_f32((unsigned short)(sv.x >> 16)),    eps1, a1 * Q8INV);
        a2 = fmaf(bf16_to_f32((unsigned short)(sv.y & 0xFFFF)), eps1, a2 * Q8INV);
        a3 = fmaf(bf16_to_f32((unsigned short)(sv.y >> 16)),    eps1, a3 * Q8INV);
        uint2 o;
        o.x = (unsigned)bf16_rne(a0) | ((unsigned)bf16_rne(a1) << 16);
        o.y = (unsigned)bf16_rne(a2) | ((unsigned)bf16_rne(a3) << 16);
        *(uint2*)&uls[row * UPITCH + sub * 4] = o;
    }
    __syncthreads();

    // ---- A-frags from bf16 u-tile ----
    short8 az[4];
#pragma unroll
    for (int ks = 0; ks < 4; ks++)
        az[ks] = *(const short8*)&uls[(wave * 16 + lrow) * UPITCH + ks * 32 + kgrp * 8];
    __syncthreads();   // frag reads done; uls reusable for z1 staging

    // ---- MFMA: W from global (32 KB, L1-resident, fragment order) ----
    f32x4 acc[8];
#pragma unroll
    for (int c = 0; c < 8; c++) acc[c] = (f32x4){0.f, 0.f, 0.f, 0.f};
#pragma unroll
    for (int ks = 0; ks < 4; ks++) {
        int fb = (ks * 4 + kgrp) * 8;
#pragma unroll
        for (int c = 0; c < 8; c++) {
            short8 whi = *(const short8*)(wt + (size_t)((fb + c) << 7) + (lrow << 3));
            acc[c] = __builtin_amdgcn_mfma_f32_16x16x32_bf16(az[ks], whi, acc[c], 0, 0, 0);
        }
    }

    // ---- epilogue: z1 bf16 out (staged through uls) + column stats ----
    float bv[8];
#pragma unroll
    for (int c = 0; c < 8; c++) bv[c] = bias[c * 16 + lrow];
    int lrb = wave * 16 + kgrp * 4;
    float ps[8], pq[8];
#pragma unroll
    for (int c = 0; c < 8; c++) { ps[c] = 0.f; pq[c] = 0.f; }
#pragma unroll
    for (int c = 0; c < 8; c++)
#pragma unroll
        for (int reg = 0; reg < 4; reg++) {
            float z = acc[c][reg] + bv[c];
            uls[(lrb + reg) * UPITCH + c * 16 + lrow] = bf16_rne(z);
            if (r0 + lrb + reg < NN) { ps[c] += z; pq[c] += z * z; }
        }
#pragma unroll
    for (int c = 0; c < 8; c++) {
        ps[c] += __shfl_xor(ps[c], 16); pq[c] += __shfl_xor(pq[c], 16);
        ps[c] += __shfl_xor(ps[c], 32); pq[c] += __shfl_xor(pq[c], 32);
    }
    if (kgrp == 0) {
#pragma unroll
        for (int c = 0; c < 8; c++) {
            atomicAdd(&stats[c * 16 + lrow], ps[c]);
            atomicAdd(&stats[HH + c * 16 + lrow], pq[c]);
        }
    }
    __syncthreads();
#pragma unroll
    for (int i = 0; i < 4; i++) {
        int idx = tid + i * 256;
        int row = idx >> 4;
        int r = r0 + row;
        if (r < NN)
            *(uint4*)(z1_out + (size_t)r * HH + (idx & 15) * 8) =
                *(const uint4*)&uls[row * UPITCH + (idx & 15) * 8];
    }
    if (tid < HH) {
        atomicAdd(&colsum[tid], stats[tid]);
        atomicAdd(&colsq[tid], stats[HH + tid]);
    }
}

// ---------------- GEMM v9 (r4 proven) + POOL fusion in the last dispatch ----------------
// MODE 0: hbf = bf16(x @ W0 + bias)                       [A fp32, split-bf16]
// MODE 2: A' = relu(BN(z1)); hbf = bf16(LN(h_old + relu(A'@W2 + bias)))   [A = z1 bf16]
// Emits int8 shadow h8 if h8out != 0. POOL=1 (last layer only): global_mean_pool partials
// accumulated straight from the LDS tile (saves the standalone 25.6 MB pool pass).
// Evidence (r6): W-from-global K-loop REGRESSED +15us/dispatch — lockstep waves expose L2
// latency with no co-resident work to hide under. Keep the LDS W stage.

template<int MODE, int POOL>
__global__ __launch_bounds__(256, 4) void gemm_v9(
    const void* __restrict__ Ain,
    const short* __restrict__ wt_hi,
    const float* __restrict__ bias,
    const float* __restrict__ colsum, const float* __restrict__ colsq,
    const float* __restrict__ bng, const float* __restrict__ bnb,
    const float* __restrict__ lng, const float* __restrict__ lnb,
    unsigned short* __restrict__ hbf,
    unsigned int* __restrict__ h8out,
    const int* __restrict__ batch,
    float* __restrict__ psum, float* __restrict__ pcnt)
{
    __shared__ short wh[HH * HH];    // 32 KB W; reused post-K-loop as bf16 row-tile stage
    __shared__ float stats[2 * HH];  // mode2: bsc|bsh
    __shared__ int bsh[64];          // POOL: staged batch ids (256 B)
    int tid = threadIdx.x;
    int wave = tid >> 6, lane = tid & 63;
    int lrow = lane & 15, kgrp = lane >> 4;
    int r0 = blockIdx.x * 64;
    int arow = r0 + wave * 16 + lrow;

    {
        const short8* src = (const short8*)wt_hi;
        short8* dst = (short8*)wh;
#pragma unroll
        for (int i = 0; i < 8; i++) dst[tid + i * 256] = src[tid + i * 256];
    }
    if (MODE == 2 && tid < HH) {
        float m = colsum[tid] * (1.f / NN);
        float v = colsq[tid] * (1.f / NN) - m * m;
        float a = bng[tid] * rsqrtf(v + BN_EPS);
        stats[tid] = a;
        stats[HH + tid] = bnb[tid] - m * a;
    }
    if (POOL && tid < 64) {
        int r = r0 + tid;
        bsh[tid] = (r < NN) ? batch[r] : -1;
    }

    float4 a0[4], a1[4];
    short8 az[4];
    if (MODE == 2) {
        const unsigned short* Az = (const unsigned short*)Ain;
        if (arow < NN) {
#pragma unroll
            for (int ks = 0; ks < 4; ks++)
                az[ks] = *(const short8*)(Az + (size_t)arow * HH + ks * 32 + kgrp * 8);
        } else {
#pragma unroll
            for (int ks = 0; ks < 4; ks++) az[ks] = (short8){0,0,0,0,0,0,0,0};
        }
    } else {
        const float* Af = (const float*)Ain;
        if (arow < NN) {
#pragma unroll
            for (int ks = 0; ks < 4; ks++) {
                int kb = ks * 32 + kgrp * 8;
                a0[ks] = *(const float4*)(Af + (size_t)arow * HH + kb);
                a1[ks] = *(const float4*)(Af + (size_t)arow * HH + kb + 4);
            }
        } else {
#pragma unroll
            for (int ks = 0; ks < 4; ks++) {
                a0[ks] = make_float4(0.f, 0.f, 0.f, 0.f);
                a1[ks] = a0[ks];
            }
        }
    }
    __syncthreads();

    f32x4 acc[8];
#pragma unroll
    for (int c = 0; c < 8; c++) acc[c] = (f32x4){0.f, 0.f, 0.f, 0.f};

#pragma unroll
    for (int ks = 0; ks < 4; ks++) {
        int fb = (ks * 4 + kgrp) * 8;
        int kb = ks * 32 + kgrp * 8;
        float av[8];
        if (MODE == 2) {
#pragma unroll
            for (int j = 0; j < 8; j++) {
                float zb = bf16_to_f32((unsigned short)az[ks][j]);
                av[j] = fmaxf(fmaf(zb, stats[kb + j], stats[HH + kb + j]), 0.f);
            }
        } else {
            av[0] = a0[ks].x; av[1] = a0[ks].y; av[2] = a0[ks].z; av[3] = a0[ks].w;
            av[4] = a1[ks].x; av[5] = a1[ks].y; av[6] = a1[ks].z; av[7] = a1[ks].w;
        }
        short8 ahi, alo;
#pragma unroll
        for (int j = 0; j < 8; j++) {
            unsigned short hb = bf16_rne(av[j]);
            ahi[j] = (short)hb;
            alo[j] = (short)bf16_rne(av[j] - bf16_to_f32(hb));
        }
#pragma unroll
        for (int c = 0; c < 8; c++) {
            short8 whi = *(const short8*)(wh + ((fb + c) << 7) + (lrow << 3));
            acc[c] = __builtin_amdgcn_mfma_f32_16x16x32_bf16(ahi, whi, acc[c], 0, 0, 0);
            acc[c] = __builtin_amdgcn_mfma_f32_16x16x32_bf16(alo, whi, acc[c], 0, 0, 0);
        }
    }

    float bv[8];
#pragma unroll
    for (int c = 0; c < 8; c++) bv[c] = bias[c * 16 + lrow];
    int lrb = wave * 16 + kgrp * 4;
    unsigned short* hst = (unsigned short*)wh;

    if (MODE == 0) {
        __syncthreads();
#pragma unroll
        for (int c = 0; c < 8; c++)
#pragma unroll
            for (int reg = 0; reg < 4; reg++)
                hst[(lrb + reg) * HH + c * 16 + lrow] = bf16_rne(acc[c][reg] + bv[c]);
        __syncthreads();
#pragma unroll
        for (int i = 0; i < 4; i++) {
            int idx = tid + i * 256;
            int r = r0 + (idx >> 4);
            if (r < NN)
                *(uint4*)(hbf + (size_t)r * HH + (idx & 15) * 8) = ((const uint4*)wh)[idx];
        }
    } else {
        float lg[8], lb[8];
#pragma unroll
        for (int c = 0; c < 8; c++) {
            lg[c] = lng[c * 16 + lrow];
            lb[c] = lnb[c * 16 + lrow];
        }
        __syncthreads();
        // coalesced load of old-h tile into LDS
#pragma unroll
        for (int i = 0; i < 4; i++) {
            int idx = tid + i * 256;
            int r = r0 + (idx >> 4);
            uint4 v = make_uint4(0, 0, 0, 0);
            if (r < NN) v = *(const uint4*)(hbf + (size_t)r * HH + (idx & 15) * 8);
            ((uint4*)wh)[idx] = v;
        }
        __syncthreads();
#pragma unroll
        for (int reg = 0; reg < 4; reg++) {
            int r = r0 + lrb + reg;
            if (r < NN) {   // uniform within each 16-lane shfl group
                float tv[8];
                float s = 0.f, q = 0.f;
#pragma unroll
                for (int c = 0; c < 8; c++) {
                    float hold = bf16_to_f32(hst[(lrb + reg) * HH + c * 16 + lrow]);
                    tv[c] = hold + fmaxf(acc[c][reg] + bv[c], 0.f);
                    s += tv[c]; q += tv[c] * tv[c];
                }
#pragma unroll
                for (int m = 1; m < 16; m <<= 1) {
                    s += __shfl_xor(s, m);
                    q += __shfl_xor(q, m);
                }
                float mu = s * (1.f / 128.f);
                float var = q * (1.f / 128.f) - mu * mu;
                float rs = rsqrtf(var + LN_EPS);
#pragma unroll
                for (int c = 0; c < 8; c++)
                    hst[(lrb + reg) * HH + c * 16 + lrow] =
                        bf16_rne((tv[c] - mu) * rs * lg[c] + lb[c]);
            }
        }
        __syncthreads();
#pragma unroll
        for (int i = 0; i < 4; i++) {
            int idx = tid + i * 256;
            int r = r0 + (idx >> 4);
            if (r < NN)
                *(uint4*)(hbf + (size_t)r * HH + (idx & 15) * 8) = ((const uint4*)wh)[idx];
        }
    }

    // ---- int8 shadow of h for the gather path (hst holds final bf16 tile) ----
    if (h8out) {
#pragma unroll
        for (int i = 0; i < 2; i++) {
            int idx = tid + i * 256;          // 512 slots: 64 rows x 8 groups of 16 feats
            int row = idx >> 3, q = idx & 7;
            int r = r0 + row;
            if (r < NN) {
                unsigned w[4];
#pragma unroll
                for (int k = 0; k < 4; k++) {
                    uint2 d = *(const uint2*)&hst[row * HH + q * 16 + k * 4];
                    float f0 = bf16_to_f32((unsigned short)(d.x & 0xFFFF));
                    float f1 = bf16_to_f32((unsigned short)(d.x >> 16));
                    float f2 = bf16_to_f32((unsigned short)(d.y & 0xFFFF));
                    float f3 = bf16_to_f32((unsigned short)(d.y >> 16));
                    int q0 = (int)rintf(fminf(fmaxf(f0 * Q8SCALE, -127.f), 127.f));
                    int q1 = (int)rintf(fminf(fmaxf(f1 * Q8SCALE, -127.f), 127.f));
                    int q2 = (int)rintf(fminf(fmaxf(f2 * Q8SCALE, -127.f), 127.f));
                    int q3 = (int)rintf(fminf(fmaxf(f3 * Q8SCALE, -127.f), 127.f));
                    w[k] = (unsigned)(q0 & 255) | ((unsigned)(q1 & 255) << 8) |
                           ((unsigned)(q2 & 255) << 16) | ((unsigned)(q3 & 255) << 24);
                }
                *(uint4*)(h8out + (size_t)r * 32 + q * 4) = make_uint4(w[0], w[1], w[2], w[3]);
            }
        }
    }

    // ---- POOL (last layer): per-graph partial sums straight from the LDS tile ----
    if (POOL) {
        int t = tid & 127;                // feature
        int hrow0 = (tid >> 7) * 32;      // rows 0..31 / 32..63
        int cur = bsh[hrow0];
        if (cur >= 0) {
            float acc2 = 0.f; int cnt = 0;
            for (int rr = 0; rr < 32; rr++) {
                int row = hrow0 + rr;
                int g = bsh[row];
                if (g < 0) break;
                if (g != cur) {
                    atomicAdd(&psum[cur * HH + t], acc2);
                    if (t == 0) atomicAdd(&pcnt[cur], (float)cnt);
                    acc2 = 0.f; cnt = 0; cur = g;
                }
                acc2 += bf16_to_f32(hst[row * HH + t]);
                cnt++;
            }
            atomicAdd(&psum[cur * HH + t], acc2);
            if (t == 0) atomicAdd(&pcnt[cur], (float)cnt);
        }
    }
}

__global__ void pool_final(const float* __restrict__ psum, const float* __restrict__ pcnt,
                           float* __restrict__ out)
{
    int i = blockIdx.x * blockDim.x + threadIdx.x;
    if (i < GG * HH) {
        float c = pcnt[i >> 7];
        out[i] = psum[i] / fmaxf(c, 1.f);
    }
}

// ---------------- launch ----------------

extern "C" void kernel_launch(void* const* d_in, const int* in_sizes, int n_in,
                              void* d_out, int out_size, void* d_ws, size_t ws_size,
                              hipStream_t stream)
{
    const float* x     = (const float*)d_in[0];
    const float* W0    = (const float*)d_in[1];
    const float* b0    = (const float*)d_in[2];
    const float* eps_l = (const float*)d_in[3];
    const float* W1    = (const float*)d_in[4];
    const float* b1    = (const float*)d_in[5];
    const float* bng   = (const float*)d_in[6];
    const float* bnb   = (const float*)d_in[7];
    const float* W2    = (const float*)d_in[8];
    const float* b2    = (const float*)d_in[9];
    const float* lng   = (const float*)d_in[10];
    const float* lnb   = (const float*)d_in[11];
    const int*   ei    = (const int*)d_in[12];
    const int*   batch = (const int*)d_in[13];
    float* out = (float*)d_out;

    char* ws = (char*)d_ws;
    size_t off = 0;
    auto alloc = [&](size_t bytes) -> void* {
        void* p = ws + off;
        off += (bytes + 255) & ~(size_t)255;
        return p;
    };
    unsigned short* hbf = (unsigned short*)alloc((size_t)NN * HH * 2);  // h (bf16)
    unsigned short* z1  = (unsigned short*)alloc((size_t)NN * HH * 2);  // z1 (bf16)
    unsigned int*   h8  = (unsigned int*)alloc((size_t)NN * HH);        // h (int8 shadow, 12.8 MB)
    int*   colidx = (int*)alloc((size_t)NBUK * CAP * 4 + 1024);         // +pad for 8-deep read
    int*   pairs  = (int*)alloc((size_t)NBUK * CAP * 4);
    int*   rp     = (int*)alloc((size_t)NN * 4);
    int*   re     = (int*)alloc((size_t)NN * 4);
    int*   bcur   = (int*)alloc((NBUK + 1) * 4);
    float* colsum = (float*)alloc((size_t)LL * HH * 2 * 4);  // [l][sum|sq][HH]
    float* psum   = (float*)alloc((size_t)GG * HH * 4);
    float* pcnt   = (float*)alloc(GG * 4);
    short* wt_hi  = (short*)alloc((size_t)9 * HH * HH * 2);

    // fused: zero colsum/psum/pcnt + bcur init + weight convert
    setup_kernel<<<(9 * HH * HH + 255) / 256, 256, 0, stream>>>(W0, W1, W2, wt_hi, bcur,
                                                                colsum, psum, pcnt);

    bucket_scatter<<<(2 * EE + BCHUNK - 1) / BCHUNK, 256, 0, stream>>>(ei, bcur, pairs);
    bucket_build<<<NBUK, 256, 0, stream>>>(pairs, bcur, rp, re, colidx);

    int gb = (NN + 63) / 64;
    // encode: h = bf16(x @ W0 + b0), + int8 shadow
    gemm_v9<0, 0><<<gb, 256, 0, stream>>>(x, wt_hi, b0,
                                          nullptr, nullptr, nullptr, nullptr, nullptr, nullptr,
                                          hbf, h8, nullptr, nullptr, nullptr);

    for (int l = 0; l < LL; l++) {
        float* cs = colsum + (size_t)l * HH * 2;
        float* cq = cs + HH;
        // z1 = bf16(((1+eps)h + sum_nb h) @ W1 + b1) + col stats  (agg from int8 shadow)
        fused_g1<<<gb, 256, 0, stream>>>((const uint2*)hbf, h8, rp, re, colidx, eps_l, l,
                                         wt_hi + (size_t)(1 + l) * HH * HH, b1 + l * HH, z1,
                                         cs, cq);
        // h = bf16(LN(h + relu(relu(BN(z1)) @ W2 + b2))), + int8 shadow (not needed last layer);
        // last layer also accumulates the global_mean_pool partials from its LDS tile.
        if (l < LL - 1)
            gemm_v9<2, 0><<<gb, 256, 0, stream>>>(z1, wt_hi + (size_t)(5 + l) * HH * HH,
                                                  b2 + l * HH,
                                                  cs, cq, bng + l * HH, bnb + l * HH,
                                                  lng + l * HH, lnb + l * HH, hbf, h8,
                                                  nullptr, nullptr, nullptr);
        else
            gemm_v9<2, 1><<<gb, 256, 0, stream>>>(z1, wt_hi + (size_t)(5 + l) * HH * HH,
                                                  b2 + l * HH,
                                                  cs, cq, bng + l * HH, bnb + l * HH,
                                                  lng + l * HH, lnb + l * HH, hbf, nullptr,
                                                  batch, psum, pcnt);
    }

    pool_final<<<(GG * HH + 255) / 256, 256, 0, stream>>>(psum, pcnt, out);
}